// Round 7
// baseline (290.595 us; speedup 1.0000x reference)
//
#include <hip/hip_runtime.h>
#include <hip/hip_bf16.h>

#define DM 768
#define NH 12
#define HD 64
#define B_ 4
#define S_ 2048
#define MT (B_*S_)   // 8192 rows

typedef unsigned short u16;
typedef __attribute__((ext_vector_type(8))) short bf16x8;
typedef __attribute__((ext_vector_type(4))) float f32x4;
typedef __attribute__((ext_vector_type(4))) short s16x4;
typedef __attribute__((ext_vector_type(4))) unsigned u32x4;

__device__ __forceinline__ u16 f2bf(float f) {
    union { float f; unsigned u; } x; x.f = f;
    unsigned r = x.u + 0x7fffu + ((x.u >> 16) & 1u);   // RNE
    return (u16)(r >> 16);
}

__device__ __forceinline__ unsigned pk2(float a, float b) {
    union { __hip_bfloat162 h; unsigned u; } cv;
    cv.h = __float22bfloat162_rn(float2{a, b});
    return cv.u;
}

// gfx950 cross-lane half-swaps (both outputs live via "+v","+v"):
__device__ __forceinline__ void swap32(unsigned& a, unsigned& b) {
    asm volatile("v_permlane32_swap_b32 %0, %1" : "+v"(a), "+v"(b));
}
__device__ __forceinline__ void swap16(unsigned& a, unsigned& b) {
    asm volatile("v_permlane16_swap_b32 %0, %1" : "+v"(a), "+v"(b));
}

#define GLD_LDS(gp, lp) \
    __builtin_amdgcn_global_load_lds( \
        (const __attribute__((address_space(1))) void*)(gp), \
        (__attribute__((address_space(3))) void*)(lp), 16, 0, 0)

// ---------------- fused fp32 -> bf16 conversions ----------------
__global__ void cvt3_kernel(const float* __restrict__ s0, const float* __restrict__ s1,
                            const float* __restrict__ s2,
                            u16* __restrict__ d0, u16* __restrict__ d1, u16* __restrict__ d2,
                            int blocksPer) {
    int sel = blockIdx.x / blocksPer;           // uniform per block
    int rel = blockIdx.x % blocksPer;
    const float* s = (sel == 0) ? s0 : (sel == 1) ? s1 : s2;
    u16* d = (sel == 0) ? d0 : (sel == 1) ? d1 : d2;
    int i = (rel * 256 + threadIdx.x) * 4;
    float4 v = *(const float4*)(s + i);
    s16x4 o;
    o.x = (short)f2bf(v.x); o.y = (short)f2bf(v.y);
    o.z = (short)f2bf(v.z); o.w = (short)f2bf(v.w);
    *(s16x4*)(d + i) = o;
}

__global__ void cvt4_kernel(const float* __restrict__ s0, const float* __restrict__ s1,
                            const float* __restrict__ s2, const float* __restrict__ s3,
                            u16* __restrict__ d0, u16* __restrict__ d1,
                            u16* __restrict__ d2, u16* __restrict__ d3,
                            int blocksPer) {
    int sel = blockIdx.x / blocksPer;
    int rel = blockIdx.x % blocksPer;
    const float* s = (sel == 0) ? s0 : (sel == 1) ? s1 : (sel == 2) ? s2 : s3;
    u16* d = (sel == 0) ? d0 : (sel == 1) ? d1 : (sel == 2) ? d2 : d3;
    int i = (rel * 256 + threadIdx.x) * 4;
    float4 v = *(const float4*)(s + i);
    s16x4 o;
    o.x = (short)f2bf(v.x); o.y = (short)f2bf(v.y);
    o.z = (short)f2bf(v.z); o.w = (short)f2bf(v.w);
    *(s16x4*)(d + i) = o;
}

// ---------------- shared 128x128-tile MFMA core (m97 structure) ----------------
__device__ __forceinline__ void gemm_core_128(
    const u16* __restrict__ A, const u16* __restrict__ B,
    int m0, int n0, u16* As, u16* Bs, f32x4 acc[4][4])
{
    const int tid = threadIdx.x;
    const int lane = tid & 63;
    const int lr = lane & 15, quad = lane >> 4;
    const int wave = tid >> 6;
    const int wm = (wave & 1) * 64, wn = (wave >> 1) * 64;

    for (int ks = 0; ks < 24; ++ks) {
        #pragma unroll
        for (int r = 0; r < 2; ++r) {
            int idx = r * 256 + tid;
            int row = idx >> 2, col = (idx & 3) * 8;
            GLD_LDS(A + (size_t)(m0 + row) * DM + ks * 32 + col, As + idx * 8);
            GLD_LDS(B + (size_t)(n0 + row) * DM + ks * 32 + col, Bs + idx * 8);
        }
        __syncthreads();
        bf16x8 a[4], b[4];
        #pragma unroll
        for (int i = 0; i < 4; ++i) a[i] = *(const bf16x8*)(As + (wm + i * 16 + lr) * 32 + quad * 8);
        #pragma unroll
        for (int j = 0; j < 4; ++j) b[j] = *(const bf16x8*)(Bs + (wn + j * 16 + lr) * 32 + quad * 8);
        #pragma unroll
        for (int i = 0; i < 4; ++i)
            #pragma unroll
            for (int j = 0; j < 4; ++j)
                acc[i][j] = __builtin_amdgcn_mfma_f32_16x16x32_bf16(a[i], b[j], acc[i][j], 0, 0, 0);
        __syncthreads();
    }
}

// ---------------- fused QKV projection GEMM (LDS-staged) ----------------
// R6 (T1): XCD-aware bijective remap: all 6 nt of one X-panel on the same XCD L2.
__global__ __launch_bounds__(256) void qkv_gemm(
    const u16* __restrict__ Xq, const u16* __restrict__ Xk, const u16* __restrict__ Xv,
    const u16* __restrict__ Wq, const u16* __restrict__ Wk, const u16* __restrict__ Wv,
    const float* __restrict__ bQ, const float* __restrict__ bK, const float* __restrict__ bV,
    u16* __restrict__ Qo, u16* __restrict__ Ko, u16* __restrict__ VTo)
{
    __shared__ __align__(16) u16 As[128 * 32];
    __shared__ __align__(16) u16 Bs[128 * 32];

    const int xcd  = blockIdx.x & 7;
    const int slot = blockIdx.x >> 3;           // 0..143
    const int nt   = slot % 6;
    const int gg   = xcd * 24 + slot / 6;       // global mt-group 0..191
    const int mat  = gg / 64;                   // uniform per block
    const int mt   = gg % 64;
    const u16* X = (mat == 0) ? Xq : (mat == 1 ? Xk : Xv);
    const u16* W = (mat == 0) ? Wq : (mat == 1 ? Wk : Wv);
    const float* bias = (mat == 0) ? bQ : (mat == 1 ? bK : bV);

    const int lane = threadIdx.x & 63;
    const int lr = lane & 15, quad = lane >> 4;
    const int wave = threadIdx.x >> 6;
    const int m0 = mt * 128 + (wave & 1) * 64;
    const int n0 = nt * 128 + (wave >> 1) * 64;

    f32x4 acc[4][4] = {};
    gemm_core_128(X, W, mt * 128, nt * 128, As, Bs, acc);

    const int bb = m0 / S_, s0 = m0 % S_, h = n0 / HD;
    if (mat < 2) {
        u16* O = (mat == 0) ? Qo : Ko;
        const float qs = (mat == 0) ? 0.18033688011112042f : 1.0f;  // (1/8)*log2(e)
        #pragma unroll
        for (int jj = 0; jj < 4; ++jj) {
            float bv = bias[n0 + jj * 16 + lr];
            #pragma unroll
            for (int i = 0; i < 4; ++i)
                #pragma unroll
                for (int r = 0; r < 4; ++r) {
                    int s = s0 + i * 16 + quad * 4 + r;
                    O[((size_t)(bb * NH + h) * S_ + s) * HD + jj * 16 + lr] = f2bf((acc[i][jj][r] + bv) * qs);
                }
        }
    } else {
        #pragma unroll
        for (int jj = 0; jj < 4; ++jj) {
            float bv = bias[n0 + jj * 16 + lr];
            #pragma unroll
            for (int i = 0; i < 4; ++i) {
                int s = s0 + i * 16 + quad * 4;
                s16x4 o;
                o.x = (short)f2bf(acc[i][jj][0] + bv);
                o.y = (short)f2bf(acc[i][jj][1] + bv);
                o.z = (short)f2bf(acc[i][jj][2] + bv);
                o.w = (short)f2bf(acc[i][jj][3] + bv);
                *(s16x4*)(VTo + ((size_t)(bb * NH + h) * HD + jj * 16 + lr) * S_ + s) = o;
            }
        }
    }
}

// ---------------- flash attention (causal, NO-max softmax) ----------------
// R7: complementary-pair blocks for perfect causal load balance. Block (bh, p)
// owns TWO 64-row chunks: low [64p, 64p+64) and high [2048-64(p+1), 2048-64p).
// Per wave: mi=0 = 16 low rows (active kt <= KT0 = p), mi=1 = 16 high rows
// (active all kt <= KT1 = 31-p). Per-wave work = (p+1)+(32-p) = 33 mi-units,
// UNIFORM across all waves/blocks, independent of dispatch order (R6 measured
// 22% occupancy = ~30% CU-tail from 2..32-tile block skew). Guards block-uniform.
// K/V staging (64-key tiles, dbuf LDS, XOR-swizzled both-sides) shared by both mi.
// Swapped QK^T + permlane in-register transpose retained.
__global__ __launch_bounds__(256, 3) void attn_kernel(
    const u16* __restrict__ Q, const u16* __restrict__ K,
    const u16* __restrict__ VT, u16* __restrict__ CTX)
{
    const int tid = threadIdx.x;
    const int wave = tid >> 6;
    const int lane = tid & 63;
    const int lr = lane & 15, quad = lane >> 4;

    const int xcd = blockIdx.x & 7;
    const int i2  = blockIdx.x >> 3;            // 0..95
    const int bh  = xcd * 6 + (i2 % 6);
    const int p   = i2 / 6;                     // 0..15 pair index (p=0 heaviest loop, first)
    const int qb0 = p * 64 + wave * 16;                 // mi=0: low-chunk 16 rows
    const int qb1 = (S_ - 64) - p * 64 + wave * 16;     // mi=1: high-chunk 16 rows
    const int KT0 = p;                          // block-uniform last tile for mi=0
    const int KT1 = 31 - p;                     // loop bound = last tile for mi=1

    const u16* Qb = Q  + (size_t)bh * S_ * HD;
    const u16* Kb = K  + (size_t)bh * S_ * HD;
    const u16* Vb = VT + (size_t)bh * HD * S_;

    // double-buffered K/V tiles: 64 rows x 64 elems bf16 each = 8KB; total 32KB
    __shared__ __align__(16) u16 kbuf[2][64 * 64];
    __shared__ __align__(16) u16 vbuf[2][64 * 64];

    bf16x8 aq[2][2];
    #pragma unroll
    for (int mi = 0; mi < 2; ++mi)
        #pragma unroll
        for (int kk = 0; kk < 2; ++kk)
            aq[mi][kk] = *(const bf16x8*)(Qb + (size_t)((mi ? qb1 : qb0) + lr) * HD + kk * 32 + quad * 8);

    f32x4 o[2][4] = {};
    f32x4 lacc[2] = {};
    bf16x8 ones;
    #pragma unroll
    for (int j = 0; j < 8; ++j) ones[j] = (short)0x3F80;   // bf16 1.0

#define STAGE_KV(b, kk0) do {                                                   \
        _Pragma("unroll")                                                       \
        for (int j = 0; j < 2; ++j) {                                           \
            int ch  = ((j * 4 + wave) << 6) + lane;                             \
            int row = ch >> 3;                                                  \
            int cl  = (ch & 7) ^ (row & 7);                                     \
            GLD_LDS(Kb + (size_t)((kk0) + row) * HD + cl * 8, &kbuf[b][ch * 8]);\
            GLD_LDS(Vb + (size_t)row * S_ + (kk0) + cl * 8, &vbuf[b][ch * 8]);  \
        }                                                                       \
    } while (0)

    STAGE_KV(0, 0);
    __syncthreads();

    for (int kt = 0; kt <= KT1; ++kt) {
        const int cur = kt & 1;
        if (kt < KT1) STAGE_KV(cur ^ 1, (kt + 1) << 6);   // prefetch next tile

        const int k0 = kt << 6;
        const bool do0 = (kt <= KT0);                      // block-uniform

        // K fragments from LDS (swizzled read) — shared by both mi
        bf16x8 bk[4][2];
        #pragma unroll
        for (int t = 0; t < 4; ++t)
            #pragma unroll
            for (int kk = 0; kk < 2; ++kk) {
                int row = t * 16 + lr;
                int cp  = (kk * 4 + quad) ^ (row & 7);
                bk[t][kk] = *(const bf16x8*)(&kbuf[cur][row * 64 + cp * 8]);
            }

        // swapped QK^T: lane holds q=lr, key=16t+quad*4+r
        f32x4 sT[2][4];
        #pragma unroll
        for (int mi = 0; mi < 2; ++mi) {
            if (mi == 0 && !do0) continue;
            #pragma unroll
            for (int t = 0; t < 4; ++t) {
                f32x4 z = {0.f, 0.f, 0.f, 0.f};
                z = __builtin_amdgcn_mfma_f32_16x16x32_bf16(bk[t][0], aq[mi][0], z, 0, 0, 0);
                z = __builtin_amdgcn_mfma_f32_16x16x32_bf16(bk[t][1], aq[mi][1], z, 0, 0, 0);
                sT[mi][t] = z;
            }
            if (kt == (mi ? KT1 : KT0)) {   // diagonal tile: causal mask (exp2(-inf)=0)
                int qrow = (mi ? qb1 : qb0) + lr;
                #pragma unroll
                for (int t = 0; t < 4; ++t)
                    #pragma unroll
                    for (int r = 0; r < 4; ++r) {
                        int key = k0 + t * 16 + quad * 4 + r;
                        if (key > qrow) sT[mi][t][r] = -INFINITY;
                    }
            }
        }

        // V fragments from LDS (swizzled read) — shared by both mi
        bf16x8 bv[4][2];
        #pragma unroll
        for (int nv = 0; nv < 4; ++nv)
            #pragma unroll
            for (int c2 = 0; c2 < 2; ++c2) {
                int row = nv * 16 + lr;
                int cp  = (c2 * 4 + quad) ^ (row & 7);
                bv[nv][c2] = *(const bf16x8*)(&vbuf[cur][row * 64 + cp * 8]);
            }

        // exp (Q pre-scaled by scale*log2e) + in-register transpose + lacc/PV
        #pragma unroll
        for (int mi = 0; mi < 2; ++mi) {
            if (mi == 0 && !do0) continue;
            #pragma unroll
            for (int t = 0; t < 4; ++t)
                #pragma unroll
                for (int r = 0; r < 4; ++r)
                    sT[mi][t][r] = exp2f(sT[mi][t][r]);

            bf16x8 pa[2];
            #pragma unroll
            for (int c = 0; c < 2; ++c) {
                unsigned u00 = pk2(sT[mi][2 * c + 0][0], sT[mi][2 * c + 0][1]);
                unsigned u01 = pk2(sT[mi][2 * c + 0][2], sT[mi][2 * c + 0][3]);
                unsigned u10 = pk2(sT[mi][2 * c + 1][0], sT[mi][2 * c + 1][1]);
                unsigned u11 = pk2(sT[mi][2 * c + 1][2], sT[mi][2 * c + 1][3]);
                swap32(u00, u10); swap16(u00, u10);
                swap32(u01, u11); swap16(u01, u11);
                u32x4 P = {u00, u01, u10, u11};
                pa[c] = __builtin_bit_cast(bf16x8, P);
            }

            lacc[mi] = __builtin_amdgcn_mfma_f32_16x16x32_bf16(pa[0], ones, lacc[mi], 0, 0, 0);
            lacc[mi] = __builtin_amdgcn_mfma_f32_16x16x32_bf16(pa[1], ones, lacc[mi], 0, 0, 0);
            #pragma unroll
            for (int nv = 0; nv < 4; ++nv) {
                o[mi][nv] = __builtin_amdgcn_mfma_f32_16x16x32_bf16(pa[0], bv[nv][0], o[mi][nv], 0, 0, 0);
                o[mi][nv] = __builtin_amdgcn_mfma_f32_16x16x32_bf16(pa[1], bv[nv][1], o[mi][nv], 0, 0, 0);
            }
        }

        __syncthreads();   // staging of kt+1 done; reads of buf[cur] done
    }
#undef STAGE_KV

    // -------- per-wave epilogue (no cross-wave reduction) --------
    const int bb = bh / NH, h = bh % NH;
    #pragma unroll
    for (int mi = 0; mi < 2; ++mi) {
        const int qb = mi ? qb1 : qb0;
        f32x4 inv;
        #pragma unroll
        for (int r = 0; r < 4; ++r) inv[r] = 1.0f / lacc[mi][r];
        #pragma unroll
        for (int nv = 0; nv < 4; ++nv)
            #pragma unroll
            for (int r = 0; r < 4; ++r)
                CTX[(size_t)(bb * S_ + qb + quad * 4 + r) * DM + h * HD + nv * 16 + lr]
                    = f2bf(o[mi][nv][r] * inv[r]);
    }
}

// ---------------- output projection GEMM (LDS-staged, fp32 out) ----------------
// R6 (T1): same XCD-aware bijective remap as qkv_gemm. 384 = 8 XCD x 8 mt x 6 nt.
__global__ __launch_bounds__(256) void o_gemm(
    const u16* __restrict__ X, const u16* __restrict__ W,
    const float* __restrict__ bias, float* __restrict__ Out)
{
    __shared__ __align__(16) u16 As[128 * 32];
    __shared__ __align__(16) u16 Bs[128 * 32];

    const int xcd  = blockIdx.x & 7;
    const int slot = blockIdx.x >> 3;           // 0..47
    const int nt   = slot % 6;
    const int mt   = xcd * 8 + slot / 6;        // 0..63
    const int lane = threadIdx.x & 63;
    const int lr = lane & 15, quad = lane >> 4;
    const int wave = threadIdx.x >> 6;
    const int m0 = mt * 128 + (wave & 1) * 64;
    const int n0 = nt * 128 + (wave >> 1) * 64;

    f32x4 acc[4][4] = {};
    gemm_core_128(X, W, mt * 128, nt * 128, As, Bs, acc);

    #pragma unroll
    for (int jj = 0; jj < 4; ++jj) {
        float bv = bias[n0 + jj * 16 + lr];
        #pragma unroll
        for (int i = 0; i < 4; ++i)
            #pragma unroll
            for (int r = 0; r < 4; ++r)
                Out[(size_t)(m0 + i * 16 + quad * 4 + r) * DM + n0 + jj * 16 + lr] = acc[i][jj][r] + bv;
    }
}

extern "C" void kernel_launch(void* const* d_in, const int* in_sizes, int n_in,
                              void* d_out, int out_size, void* d_ws, size_t ws_size,
                              hipStream_t stream) {
    const float* q  = (const float*)d_in[0];
    const float* k  = (const float*)d_in[1];
    const float* v  = (const float*)d_in[2];
    const float* WQ = (const float*)d_in[3];
    const float* bQ = (const float*)d_in[4];
    const float* WK = (const float*)d_in[5];
    const float* bK = (const float*)d_in[6];
    const float* WV = (const float*)d_in[7];
    const float* bV = (const float*)d_in[8];
    const float* WO = (const float*)d_in[9];
    const float* bO = (const float*)d_in[10];

    char* ws = (char*)d_ws;
    const size_t SZ_X = (size_t)MT * DM * 2;   // 12,582,912 B
    const size_t SZ_W = (size_t)DM * DM * 2;   //  1,179,648 B
    u16* Xq = (u16*)(ws);
    u16* Xk = (u16*)(ws + SZ_X);
    u16* Xv = (u16*)(ws + 2 * SZ_X);
    u16* Wq = (u16*)(ws + 3 * SZ_X);
    u16* Wk = (u16*)(ws + 3 * SZ_X + SZ_W);
    u16* Wv = (u16*)(ws + 3 * SZ_X + 2 * SZ_W);
    u16* Wo = (u16*)(ws + 3 * SZ_X + 3 * SZ_W);
    u16* Qh  = (u16*)(ws + 3 * SZ_X + 4 * SZ_W);
    u16* Kh  = (u16*)(ws + 4 * SZ_X + 4 * SZ_W);
    u16* VTh = (u16*)(ws + 5 * SZ_X + 4 * SZ_W);
    u16* CTX = Xq;   // Xq dead after qkv_gemm; reuse

    const int nX = MT * DM;    // 6,291,456
    const int nW = DM * DM;    //   589,824
    cvt3_kernel<<<3 * (nX / 1024), 256, 0, stream>>>(q, k, v, Xq, Xk, Xv, nX / 1024);
    cvt4_kernel<<<4 * (nW / 1024), 256, 0, stream>>>(WQ, WK, WV, WO, Wq, Wk, Wv, Wo, nW / 1024);

    qkv_gemm<<<1152, 256, 0, stream>>>(Xq, Xk, Xv, Wq, Wk, Wv, bQ, bK, bV, Qh, Kh, VTh);
    attn_kernel<<<768, 256, 0, stream>>>(Qh, Kh, VTh, CTX);
    o_gemm<<<384, 256, 0, stream>>>(CTX, Wo, bO, (float*)d_out);
}

// Round 8
// 267.249 us; speedup vs baseline: 1.0874x; 1.0874x over previous
//
#include <hip/hip_runtime.h>
#include <hip/hip_bf16.h>

#define DM 768
#define NH 12
#define HD 64
#define B_ 4
#define S_ 2048
#define MT (B_*S_)   // 8192 rows

typedef unsigned short u16;
typedef __attribute__((ext_vector_type(8))) short bf16x8;
typedef __attribute__((ext_vector_type(4))) float f32x4;
typedef __attribute__((ext_vector_type(4))) short s16x4;
typedef __attribute__((ext_vector_type(4))) unsigned u32x4;

__device__ __forceinline__ u16 f2bf(float f) {
    union { float f; unsigned u; } x; x.f = f;
    unsigned r = x.u + 0x7fffu + ((x.u >> 16) & 1u);   // RNE
    return (u16)(r >> 16);
}

__device__ __forceinline__ unsigned pk2(float a, float b) {
    union { __hip_bfloat162 h; unsigned u; } cv;
    cv.h = __float22bfloat162_rn(float2{a, b});
    return cv.u;
}

// gfx950 cross-lane half-swaps (both outputs live via "+v","+v"):
__device__ __forceinline__ void swap32(unsigned& a, unsigned& b) {
    asm volatile("v_permlane32_swap_b32 %0, %1" : "+v"(a), "+v"(b));
}
__device__ __forceinline__ void swap16(unsigned& a, unsigned& b) {
    asm volatile("v_permlane16_swap_b32 %0, %1" : "+v"(a), "+v"(b));
}

#define GLD_LDS(gp, lp) \
    __builtin_amdgcn_global_load_lds( \
        (const __attribute__((address_space(1))) void*)(gp), \
        (__attribute__((address_space(3))) void*)(lp), 16, 0, 0)

// ---------------- single fused fp32 -> bf16 conversion kernel (R8: was cvt3+cvt4) ----------------
// 7 tensors in one dispatch: 3 activations (nX each) + 4 weights (nW each).
// One fewer kernel launch; W-conversions run concurrently with X-conversions.
__global__ void cvt_all(const float* __restrict__ x0, const float* __restrict__ x1,
                        const float* __restrict__ x2,
                        const float* __restrict__ w0, const float* __restrict__ w1,
                        const float* __restrict__ w2, const float* __restrict__ w3,
                        u16* __restrict__ dx0, u16* __restrict__ dx1, u16* __restrict__ dx2,
                        u16* __restrict__ dw0, u16* __restrict__ dw1,
                        u16* __restrict__ dw2, u16* __restrict__ dw3,
                        int xBlocks, int wBlocks) {
    const float* s;
    u16* d;
    int rel;
    if ((int)blockIdx.x < 3 * xBlocks) {
        int sel = blockIdx.x / xBlocks;
        rel = blockIdx.x % xBlocks;
        s = (sel == 0) ? x0 : (sel == 1) ? x1 : x2;
        d = (sel == 0) ? dx0 : (sel == 1) ? dx1 : dx2;
    } else {
        int wb = blockIdx.x - 3 * xBlocks;
        int sel = wb / wBlocks;
        rel = wb % wBlocks;
        s = (sel == 0) ? w0 : (sel == 1) ? w1 : (sel == 2) ? w2 : w3;
        d = (sel == 0) ? dw0 : (sel == 1) ? dw1 : (sel == 2) ? dw2 : dw3;
    }
    int i = (rel * 256 + threadIdx.x) * 4;
    float4 v = *(const float4*)(s + i);
    s16x4 o;
    o.x = (short)f2bf(v.x); o.y = (short)f2bf(v.y);
    o.z = (short)f2bf(v.z); o.w = (short)f2bf(v.w);
    *(s16x4*)(d + i) = o;
}

// ---------------- shared 128x128-tile MFMA core (m97 structure) ----------------
__device__ __forceinline__ void gemm_core_128(
    const u16* __restrict__ A, const u16* __restrict__ B,
    int m0, int n0, u16* As, u16* Bs, f32x4 acc[4][4])
{
    const int tid = threadIdx.x;
    const int lane = tid & 63;
    const int lr = lane & 15, quad = lane >> 4;
    const int wave = tid >> 6;
    const int wm = (wave & 1) * 64, wn = (wave >> 1) * 64;

    for (int ks = 0; ks < 24; ++ks) {
        #pragma unroll
        for (int r = 0; r < 2; ++r) {
            int idx = r * 256 + tid;
            int row = idx >> 2, col = (idx & 3) * 8;
            GLD_LDS(A + (size_t)(m0 + row) * DM + ks * 32 + col, As + idx * 8);
            GLD_LDS(B + (size_t)(n0 + row) * DM + ks * 32 + col, Bs + idx * 8);
        }
        __syncthreads();
        bf16x8 a[4], b[4];
        #pragma unroll
        for (int i = 0; i < 4; ++i) a[i] = *(const bf16x8*)(As + (wm + i * 16 + lr) * 32 + quad * 8);
        #pragma unroll
        for (int j = 0; j < 4; ++j) b[j] = *(const bf16x8*)(Bs + (wn + j * 16 + lr) * 32 + quad * 8);
        #pragma unroll
        for (int i = 0; i < 4; ++i)
            #pragma unroll
            for (int j = 0; j < 4; ++j)
                acc[i][j] = __builtin_amdgcn_mfma_f32_16x16x32_bf16(a[i], b[j], acc[i][j], 0, 0, 0);
        __syncthreads();
    }
}

// ---------------- fused QKV projection GEMM (LDS-staged) ----------------
// R6 (T1): XCD-aware bijective remap: all 6 nt of one X-panel on the same XCD L2.
__global__ __launch_bounds__(256) void qkv_gemm(
    const u16* __restrict__ Xq, const u16* __restrict__ Xk, const u16* __restrict__ Xv,
    const u16* __restrict__ Wq, const u16* __restrict__ Wk, const u16* __restrict__ Wv,
    const float* __restrict__ bQ, const float* __restrict__ bK, const float* __restrict__ bV,
    u16* __restrict__ Qo, u16* __restrict__ Ko, u16* __restrict__ VTo)
{
    __shared__ __align__(16) u16 As[128 * 32];
    __shared__ __align__(16) u16 Bs[128 * 32];

    const int xcd  = blockIdx.x & 7;
    const int slot = blockIdx.x >> 3;           // 0..143
    const int nt   = slot % 6;
    const int gg   = xcd * 24 + slot / 6;       // global mt-group 0..191
    const int mat  = gg / 64;                   // uniform per block
    const int mt   = gg % 64;
    const u16* X = (mat == 0) ? Xq : (mat == 1 ? Xk : Xv);
    const u16* W = (mat == 0) ? Wq : (mat == 1 ? Wk : Wv);
    const float* bias = (mat == 0) ? bQ : (mat == 1 ? bK : bV);

    const int lane = threadIdx.x & 63;
    const int lr = lane & 15, quad = lane >> 4;
    const int wave = threadIdx.x >> 6;
    const int m0 = mt * 128 + (wave & 1) * 64;
    const int n0 = nt * 128 + (wave >> 1) * 64;

    f32x4 acc[4][4] = {};
    gemm_core_128(X, W, mt * 128, nt * 128, As, Bs, acc);

    const int bb = m0 / S_, s0 = m0 % S_, h = n0 / HD;
    if (mat < 2) {
        u16* O = (mat == 0) ? Qo : Ko;
        const float qs = (mat == 0) ? 0.18033688011112042f : 1.0f;  // (1/8)*log2(e)
        #pragma unroll
        for (int jj = 0; jj < 4; ++jj) {
            float bv = bias[n0 + jj * 16 + lr];
            #pragma unroll
            for (int i = 0; i < 4; ++i)
                #pragma unroll
                for (int r = 0; r < 4; ++r) {
                    int s = s0 + i * 16 + quad * 4 + r;
                    O[((size_t)(bb * NH + h) * S_ + s) * HD + jj * 16 + lr] = f2bf((acc[i][jj][r] + bv) * qs);
                }
        }
    } else {
        #pragma unroll
        for (int jj = 0; jj < 4; ++jj) {
            float bv = bias[n0 + jj * 16 + lr];
            #pragma unroll
            for (int i = 0; i < 4; ++i) {
                int s = s0 + i * 16 + quad * 4;
                s16x4 o;
                o.x = (short)f2bf(acc[i][jj][0] + bv);
                o.y = (short)f2bf(acc[i][jj][1] + bv);
                o.z = (short)f2bf(acc[i][jj][2] + bv);
                o.w = (short)f2bf(acc[i][jj][3] + bv);
                *(s16x4*)(VTo + ((size_t)(bb * NH + h) * HD + jj * 16 + lr) * S_ + s) = o;
            }
        }
    }
}

// ---------------- flash attention (causal, NO-max softmax) ----------------
// R8 = R6 structure EXACTLY (R7's complementary pairing regressed: spill + 44% more
// fixed-cost iterations). Block owns 128 q-rows (4 waves x 32); K/V tile staged once
// per block into double-buffered LDS via 16 coalesced global_load_lds; one barrier
// per tile; XOR swizzle both-sides; swapped QK^T + permlane in-register transpose;
// per-wave epilogue.
__global__ __launch_bounds__(256, 3) void attn_kernel(
    const u16* __restrict__ Q, const u16* __restrict__ K,
    const u16* __restrict__ VT, u16* __restrict__ CTX)
{
    const int tid = threadIdx.x;
    const int wave = tid >> 6;
    const int lane = tid & 63;
    const int lr = lane & 15, quad = lane >> 4;

    const int xcd = blockIdx.x & 7;
    const int i2  = blockIdx.x >> 3;            // 0..95
    const int bh  = xcd * 6 + (i2 % 6);
    const int qc  = 15 - (i2 / 6);              // longest q-chunks first
    const int Q0  = qc * 128;
    const int q0w = Q0 + wave * 32;             // this wave's 32 q-rows

    const u16* Qb = Q  + (size_t)bh * S_ * HD;
    const u16* Kb = K  + (size_t)bh * S_ * HD;
    const u16* Vb = VT + (size_t)bh * HD * S_;

    // double-buffered K/V tiles: 64 rows x 64 elems bf16 each = 8KB; total 32KB
    __shared__ __align__(16) u16 kbuf[2][64 * 64];
    __shared__ __align__(16) u16 vbuf[2][64 * 64];

    bf16x8 aq[2][2];
    #pragma unroll
    for (int mi = 0; mi < 2; ++mi)
        #pragma unroll
        for (int kk = 0; kk < 2; ++kk)
            aq[mi][kk] = *(const bf16x8*)(Qb + (size_t)(q0w + mi * 16 + lr) * HD + kk * 32 + quad * 8);

    f32x4 o[2][4] = {};
    f32x4 lacc[2] = {};
    bf16x8 ones;
    #pragma unroll
    for (int j = 0; j < 8; ++j) ones[j] = (short)0x3F80;   // bf16 1.0

    const int KT  = 2 * qc + 1;                 // block-uniform last tile
    const int ktw = (q0w + 31) >> 6;            // this wave's last tile

#define STAGE_KV(b, kk0) do {                                                   \
        _Pragma("unroll")                                                       \
        for (int j = 0; j < 2; ++j) {                                           \
            int ch  = ((j * 4 + wave) << 6) + lane;                             \
            int row = ch >> 3;                                                  \
            int cl  = (ch & 7) ^ (row & 7);                                     \
            GLD_LDS(Kb + (size_t)((kk0) + row) * HD + cl * 8, &kbuf[b][ch * 8]);\
            GLD_LDS(Vb + (size_t)row * S_ + (kk0) + cl * 8, &vbuf[b][ch * 8]);  \
        }                                                                       \
    } while (0)

    STAGE_KV(0, 0);
    __syncthreads();

    for (int kt = 0; kt <= KT; ++kt) {
        const int cur = kt & 1;
        if (kt < KT) STAGE_KV(cur ^ 1, (kt + 1) << 6);   // prefetch next tile

        if (kt <= ktw) {                                  // wave-uniform guard
            const int k0 = kt << 6;

            // K fragments from LDS (swizzled read)
            bf16x8 bk[4][2];
            #pragma unroll
            for (int t = 0; t < 4; ++t)
                #pragma unroll
                for (int kk = 0; kk < 2; ++kk) {
                    int row = t * 16 + lr;
                    int cp  = (kk * 4 + quad) ^ (row & 7);
                    bk[t][kk] = *(const bf16x8*)(&kbuf[cur][row * 64 + cp * 8]);
                }

            // swapped QK^T: lane holds q=lr, key=16t+quad*4+r
            f32x4 sT[2][4];
            #pragma unroll
            for (int mi = 0; mi < 2; ++mi)
                #pragma unroll
                for (int t = 0; t < 4; ++t) {
                    f32x4 z = {0.f, 0.f, 0.f, 0.f};
                    z = __builtin_amdgcn_mfma_f32_16x16x32_bf16(bk[t][0], aq[mi][0], z, 0, 0, 0);
                    z = __builtin_amdgcn_mfma_f32_16x16x32_bf16(bk[t][1], aq[mi][1], z, 0, 0, 0);
                    sT[mi][t] = z;
                }

            if (kt == ktw) {   // diagonal tile: causal mask (exp2(-inf) = 0)
                #pragma unroll
                for (int mi = 0; mi < 2; ++mi) {
                    int qrow = q0w + mi * 16 + lr;
                    #pragma unroll
                    for (int t = 0; t < 4; ++t)
                        #pragma unroll
                        for (int r = 0; r < 4; ++r) {
                            int key = k0 + t * 16 + quad * 4 + r;
                            if (key > qrow) sT[mi][t][r] = -INFINITY;
                        }
                }
            }

            // V fragments from LDS (swizzled read)
            bf16x8 bv[4][2];
            #pragma unroll
            for (int nv = 0; nv < 4; ++nv)
                #pragma unroll
                for (int c2 = 0; c2 < 2; ++c2) {
                    int row = nv * 16 + lr;
                    int cp  = (c2 * 4 + quad) ^ (row & 7);
                    bv[nv][c2] = *(const bf16x8*)(&vbuf[cur][row * 64 + cp * 8]);
                }

            // exp (Q pre-scaled by scale*log2e) + in-register transpose to A-layout
            bf16x8 pa[2][2];
            #pragma unroll
            for (int mi = 0; mi < 2; ++mi) {
                #pragma unroll
                for (int t = 0; t < 4; ++t)
                    #pragma unroll
                    for (int r = 0; r < 4; ++r)
                        sT[mi][t][r] = exp2f(sT[mi][t][r]);

                #pragma unroll
                for (int c = 0; c < 2; ++c) {
                    unsigned u00 = pk2(sT[mi][2 * c + 0][0], sT[mi][2 * c + 0][1]);
                    unsigned u01 = pk2(sT[mi][2 * c + 0][2], sT[mi][2 * c + 0][3]);
                    unsigned u10 = pk2(sT[mi][2 * c + 1][0], sT[mi][2 * c + 1][1]);
                    unsigned u11 = pk2(sT[mi][2 * c + 1][2], sT[mi][2 * c + 1][3]);
                    swap32(u00, u10); swap16(u00, u10);
                    swap32(u01, u11); swap16(u01, u11);
                    u32x4 P = {u00, u01, u10, u11};
                    pa[mi][c] = __builtin_bit_cast(bf16x8, P);
                }
            }

            #pragma unroll
            for (int mi = 0; mi < 2; ++mi) {
                lacc[mi] = __builtin_amdgcn_mfma_f32_16x16x32_bf16(pa[mi][0], ones, lacc[mi], 0, 0, 0);
                lacc[mi] = __builtin_amdgcn_mfma_f32_16x16x32_bf16(pa[mi][1], ones, lacc[mi], 0, 0, 0);
                #pragma unroll
                for (int nv = 0; nv < 4; ++nv) {
                    o[mi][nv] = __builtin_amdgcn_mfma_f32_16x16x32_bf16(pa[mi][0], bv[nv][0], o[mi][nv], 0, 0, 0);
                    o[mi][nv] = __builtin_amdgcn_mfma_f32_16x16x32_bf16(pa[mi][1], bv[nv][1], o[mi][nv], 0, 0, 0);
                }
            }
        }

        __syncthreads();   // staging of kt+1 done; reads of buf[cur] done
    }
#undef STAGE_KV

    // -------- per-wave epilogue (no cross-wave reduction) --------
    const int bb = bh / NH, h = bh % NH;
    #pragma unroll
    for (int mi = 0; mi < 2; ++mi) {
        f32x4 inv;
        #pragma unroll
        for (int r = 0; r < 4; ++r) inv[r] = 1.0f / lacc[mi][r];
        #pragma unroll
        for (int nv = 0; nv < 4; ++nv)
            #pragma unroll
            for (int r = 0; r < 4; ++r)
                CTX[(size_t)(bb * S_ + q0w + mi * 16 + quad * 4 + r) * DM + h * HD + nv * 16 + lr]
                    = f2bf(o[mi][nv][r] * inv[r]);
    }
}

// ---------------- output projection GEMM (LDS-staged, fp32 out) ----------------
// R6 (T1): same XCD-aware bijective remap as qkv_gemm. 384 = 8 XCD x 8 mt x 6 nt.
__global__ __launch_bounds__(256) void o_gemm(
    const u16* __restrict__ X, const u16* __restrict__ W,
    const float* __restrict__ bias, float* __restrict__ Out)
{
    __shared__ __align__(16) u16 As[128 * 32];
    __shared__ __align__(16) u16 Bs[128 * 32];

    const int xcd  = blockIdx.x & 7;
    const int slot = blockIdx.x >> 3;           // 0..47
    const int nt   = slot % 6;
    const int mt   = xcd * 8 + slot / 6;        // 0..63
    const int lane = threadIdx.x & 63;
    const int lr = lane & 15, quad = lane >> 4;
    const int wave = threadIdx.x >> 6;
    const int m0 = mt * 128 + (wave & 1) * 64;
    const int n0 = nt * 128 + (wave >> 1) * 64;

    f32x4 acc[4][4] = {};
    gemm_core_128(X, W, mt * 128, nt * 128, As, Bs, acc);

    #pragma unroll
    for (int jj = 0; jj < 4; ++jj) {
        float bv = bias[n0 + jj * 16 + lr];
        #pragma unroll
        for (int i = 0; i < 4; ++i)
            #pragma unroll
            for (int r = 0; r < 4; ++r)
                Out[(size_t)(m0 + i * 16 + quad * 4 + r) * DM + n0 + jj * 16 + lr] = acc[i][jj][r] + bv;
    }
}

extern "C" void kernel_launch(void* const* d_in, const int* in_sizes, int n_in,
                              void* d_out, int out_size, void* d_ws, size_t ws_size,
                              hipStream_t stream) {
    const float* q  = (const float*)d_in[0];
    const float* k  = (const float*)d_in[1];
    const float* v  = (const float*)d_in[2];
    const float* WQ = (const float*)d_in[3];
    const float* bQ = (const float*)d_in[4];
    const float* WK = (const float*)d_in[5];
    const float* bK = (const float*)d_in[6];
    const float* WV = (const float*)d_in[7];
    const float* bV = (const float*)d_in[8];
    const float* WO = (const float*)d_in[9];
    const float* bO = (const float*)d_in[10];

    char* ws = (char*)d_ws;
    const size_t SZ_X = (size_t)MT * DM * 2;   // 12,582,912 B
    const size_t SZ_W = (size_t)DM * DM * 2;   //  1,179,648 B
    u16* Xq = (u16*)(ws);
    u16* Xk = (u16*)(ws + SZ_X);
    u16* Xv = (u16*)(ws + 2 * SZ_X);
    u16* Wq = (u16*)(ws + 3 * SZ_X);
    u16* Wk = (u16*)(ws + 3 * SZ_X + SZ_W);
    u16* Wv = (u16*)(ws + 3 * SZ_X + 2 * SZ_W);
    u16* Wo = (u16*)(ws + 3 * SZ_X + 3 * SZ_W);
    u16* Qh  = (u16*)(ws + 3 * SZ_X + 4 * SZ_W);
    u16* Kh  = (u16*)(ws + 4 * SZ_X + 4 * SZ_W);
    u16* VTh = (u16*)(ws + 5 * SZ_X + 4 * SZ_W);
    u16* CTX = Xq;   // Xq dead after qkv_gemm; reuse

    const int nX = MT * DM;    // 6,291,456
    const int nW = DM * DM;    //   589,824
    const int xB = nX / 1024;  // 6144
    const int wB = nW / 1024;  //  576
    cvt_all<<<3 * xB + 4 * wB, 256, 0, stream>>>(q, k, v, WQ, WK, WV, WO,
                                                 Xq, Xk, Xv, Wq, Wk, Wv, Wo, xB, wB);

    qkv_gemm<<<1152, 256, 0, stream>>>(Xq, Xk, Xv, Wq, Wk, Wv, bQ, bK, bV, Qh, Kh, VTh);
    attn_kernel<<<768, 256, 0, stream>>>(Qh, Kh, VTh, CTX);
    o_gemm<<<384, 256, 0, stream>>>(CTX, Wo, bO, (float*)d_out);
}